// Round 7
// baseline (633.648 us; speedup 1.0000x reference)
//
#include <hip/hip_runtime.h>
#include <cstdint>
#include <cstddef>

// Problem constants
#define T_TOK 4096
#define DIM   1024
#define NEXP  8
#define HID   2730
#define HP2   2816          // hidden padded to 88*32 = 22*128
#define NB1   5632          // 2*HP2 rows (gate || up) in transposed B1
#define NPAIR (T_TOK*2)

typedef __attribute__((ext_vector_type(8))) short short8;
typedef __attribute__((ext_vector_type(4))) float f32x4;

// ws layout (bytes)
#define OFF_CNT   0UL
#define OFF_USE   64UL
#define OFF_Z     96UL
#define OFF_OFFS  160UL                                   // 8 ints (prefix offsets)
#define OFF_LIST  256UL                                   // 8*4096 ints
#define OFF_PAIRW 131328UL                                // 8192 floats
#define OFF_XB    164096UL                                // 4096*1024 bf16
#define OFF_H     (OFF_XB + 8388608UL)                    // 8192*2816 bf16 (slot-compacted)
#define OFF_B2    (OFF_H + 46137344UL)                    // 8*1024*2816 bf16
#define OFF_B1    (OFF_B2 + 46137344UL)                   // 8*5632*1024 bf16
#define OFF_OP    OFF_B1                                  // overlay: 8192*1024 bf16 (B1 dead after gemm1)

__device__ __forceinline__ unsigned short f2bf(float f) {
    unsigned u = __float_as_uint(f);
    return (unsigned short)((u + 0x7FFFu + ((u >> 16) & 1u)) >> 16);
}

__device__ __forceinline__ unsigned pack2(float a, float b) {
    return (unsigned)f2bf(a) | ((unsigned)f2bf(b) << 16);
}

__device__ __forceinline__ void load_lds16(const void* g, void* l) {
    __builtin_amdgcn_global_load_lds(
        (const __attribute__((address_space(1))) void*)g,
        (__attribute__((address_space(3))) void*)l, 16, 0, 0);
}

struct __align__(8) us4 { unsigned short x, y, z, w; };
struct __align__(8) u32x2 { unsigned x, y; };

// ---------------------------------------------------------------------------
// Router (fp32, exact) + x->bf16 conversion fused. s_rw transposed to [e][d]
// so the inner-loop LDS read is lane-stride-1 (conflict-free).
// ---------------------------------------------------------------------------
__global__ __launch_bounds__(256) void router_kernel(
    const float* __restrict__ x, const float* __restrict__ rw,
    int* __restrict__ counts, float* __restrict__ usage, float* __restrict__ zacc,
    int* __restrict__ lists, float* __restrict__ pairw,
    unsigned short* __restrict__ xb)
{
    __shared__ float s_rw[NEXP][DIM];   // transposed
    __shared__ float s_use[NEXP];
    __shared__ float s_z;
    const int tid = threadIdx.x;
    for (int i = tid; i < DIM * NEXP; i += 256) s_rw[i & 7][i >> 3] = rw[i];
    if (tid < NEXP) s_use[tid] = 0.f;
    if (tid == NEXP) s_z = 0.f;
    __syncthreads();

    const int wave = tid >> 6, lane = tid & 63;
    const int t = blockIdx.x * 4 + wave;

    float acc[NEXP];
    #pragma unroll
    for (int e = 0; e < NEXP; ++e) acc[e] = 0.f;
    #pragma unroll
    for (int j = 0; j < DIM / 64; ++j) {
        const int d = j * 64 + lane;
        const float xv = x[(size_t)t * DIM + d];
        xb[(size_t)t * DIM + d] = f2bf(xv);
        #pragma unroll
        for (int e = 0; e < NEXP; ++e) acc[e] = fmaf(xv, s_rw[e][d], acc[e]);
    }
    #pragma unroll
    for (int e = 0; e < NEXP; ++e) {
        float v = acc[e];
        for (int off = 32; off > 0; off >>= 1) v += __shfl_down(v, off, 64);
        acc[e] = v;
    }
    if (lane == 0) {
        float l[NEXP];
        #pragma unroll
        for (int e = 0; e < NEXP; ++e) l[e] = acc[e];
        float m = l[0];
        #pragma unroll
        for (int e = 1; e < NEXP; ++e) m = fmaxf(m, l[e]);
        float se = 0.f;
        #pragma unroll
        for (int e = 0; e < NEXP; ++e) se += __expf(l[e] - m);
        const float lse = m + __logf(se);
        #pragma unroll
        for (int e = 0; e < NEXP; ++e) atomicAdd(&s_use[e], __expf(l[e] - m) / se);
        atomicAdd(&s_z, lse * lse);
        int i0 = 0; float l0 = l[0];
        #pragma unroll
        for (int e = 1; e < NEXP; ++e) if (l[e] > l0) { l0 = l[e]; i0 = e; }
        int i1 = -1; float l1 = -1e30f;
        #pragma unroll
        for (int e = 0; e < NEXP; ++e) if (e != i0 && l[e] > l1) { l1 = l[e]; i1 = e; }
        const float p0 = 1.f / (1.f + __expf(l1 - l0));
        const float p1 = 1.f - p0;
        const int pos0 = atomicAdd(&counts[i0], 1);
        lists[i0 * T_TOK + pos0] = (t << 1);
        const int pos1 = atomicAdd(&counts[i1], 1);
        lists[i1 * T_TOK + pos1] = (t << 1) | 1;
        pairw[2 * t]     = p0;
        pairw[2 * t + 1] = p1;
    }
    __syncthreads();
    if (tid < NEXP) atomicAdd(&usage[tid], s_use[tid]);
    if (tid == NEXP) atomicAdd(zacc, s_z);
}

__global__ void finalize_kernel(const int* __restrict__ counts,
                                const float* __restrict__ usage,
                                const float* __restrict__ zacc,
                                int* __restrict__ offs,
                                float* __restrict__ out)
{
    if (threadIdx.x == 0 && blockIdx.x == 0) {
        int o = 0;
        for (int e = 0; e < NEXP; ++e) { offs[e] = o; o += counts[e]; }
        float s = 0.f;
        for (int e = 0; e < NEXP; ++e) {
            const float u = usage[e] / (float)T_TOK;
            s += u * u;
        }
        out[(size_t)T_TOK * DIM]     = (float)NEXP * s;
        out[(size_t)T_TOK * DIM + 1] = zacc[0] / (float)T_TOK;
    }
}

// ---------------------------------------------------------------------------
// Weight conversions v4: in-register 4x4 transpose, bf16 LDS, swizzled.
// ---------------------------------------------------------------------------
__global__ __launch_bounds__(256) void conv_w1_kernel(
    const float* __restrict__ wg, const float* __restrict__ wu,
    unsigned short* __restrict__ B1)
{
    __shared__ unsigned short lg[128 * 128];   // [h][k] swizzled, 32 KB
    __shared__ unsigned short lu[128 * 128];
    const int e = blockIdx.z;
    const int h0 = blockIdx.x * 128;  // n dim (HID, padded to HP2)
    const int k0 = blockIdx.y * 128;  // k dim (DIM)
    const int tid = threadIdx.x;
    const size_t wb = (size_t)e * DIM * HID;

    const int hu = (tid & 31) * 4;    // h col window (4 wide)
    const int kg = tid >> 5;          // 0..7
    const bool full = (h0 + 128 <= HID);

    #pragma unroll
    for (int uu = 0; uu < 4; ++uu) {
        const int kk = (kg * 4 + uu) * 4;   // local k row base (0..124, step 4)
        f32x4 g[4], u[4];
        if (full) {
            #pragma unroll
            for (int j = 0; j < 4; ++j) {
                const size_t src = wb + (size_t)(k0 + kk + j) * HID + h0 + hu;
                g[j] = *(const f32x4*)&wg[src];
                u[j] = *(const f32x4*)&wu[src];
            }
        } else {
            #pragma unroll
            for (int j = 0; j < 4; ++j) {
                #pragma unroll
                for (int c = 0; c < 4; ++c) {
                    const int hh = h0 + hu + c;
                    float gv = 0.f, uv = 0.f;
                    if (hh < HID) {
                        const size_t src = wb + (size_t)(k0 + kk + j) * HID + hh;
                        gv = wg[src]; uv = wu[src];
                    }
                    g[j][c] = gv; u[j][c] = uv;
                }
            }
        }
        #pragma unroll
        for (int i = 0; i < 4; ++i) {
            const int h = hu + i;
            const int byte = (((h * 128 + kk) * 2) ^ ((h & 15) << 4));
            u32x2 vg; vg.x = pack2(g[0][i], g[1][i]); vg.y = pack2(g[2][i], g[3][i]);
            u32x2 vu; vu.x = pack2(u[0][i], u[1][i]); vu.y = pack2(u[2][i], u[3][i]);
            *(u32x2*)((char*)lg + byte) = vg;
            *(u32x2*)((char*)lu + byte) = vu;
        }
    }
    __syncthreads();

    const int kc  = (tid & 15) * 8;   // k col (16 lanes x 16B = 256B/row)
    const int hrb = tid >> 4;         // output-row base 0..15
    #pragma unroll
    for (int wo = 0; wo < 8; ++wo) {
        const int h = hrb + wo * 16;
        const int byte = (((h * 128 + kc) * 2) ^ ((h & 15) << 4));
        const short8 vg = *(const short8*)((const char*)lg + byte);
        const short8 vu = *(const short8*)((const char*)lu + byte);
        *(short8*)&B1[((size_t)e * NB1 + h0 + h) * DIM + k0 + kc] = vg;
        *(short8*)&B1[((size_t)e * NB1 + HP2 + h0 + h) * DIM + k0 + kc] = vu;
    }
}

// conv_w2: B2[e][d][kh] = bf16(wd[e][kh][d]); k-rows kh in [HID,HP2) zeroed.
__global__ __launch_bounds__(256) void conv_w2_kernel(
    const float* __restrict__ wd, unsigned short* __restrict__ B2)
{
    __shared__ unsigned short lw[128 * 128];   // [d][h] swizzled
    const int e = blockIdx.z;
    const int h0 = blockIdx.x * 128;  // k dim of B2 (= wd row)
    const int d0 = blockIdx.y * 128;  // n dim (= wd col)
    const int tid = threadIdx.x;
    const size_t wb = (size_t)e * HID * DIM;

    const int du = (tid & 31) * 4;
    const int kg = tid >> 5;

    #pragma unroll
    for (int uu = 0; uu < 4; ++uu) {
        const int kk = (kg * 4 + uu) * 4;
        f32x4 v[4];
        #pragma unroll
        for (int j = 0; j < 4; ++j) {
            const int hh = h0 + kk + j;
            if (hh < HID) v[j] = *(const f32x4*)&wd[wb + (size_t)hh * DIM + d0 + du];
            else          v[j] = (f32x4)0.f;
        }
        #pragma unroll
        for (int i = 0; i < 4; ++i) {
            const int d = du + i;
            const int byte = (((d * 128 + kk) * 2) ^ ((d & 15) << 4));
            u32x2 vv; vv.x = pack2(v[0][i], v[1][i]); vv.y = pack2(v[2][i], v[3][i]);
            *(u32x2*)((char*)lw + byte) = vv;
        }
    }
    __syncthreads();

    const int kc  = (tid & 15) * 8;
    const int drb = tid >> 4;
    #pragma unroll
    for (int wo = 0; wo < 8; ++wo) {
        const int d = drb + wo * 16;
        const int byte = (((d * 128 + kc) * 2) ^ ((d & 15) << 4));
        const short8 vv = *(const short8*)((const char*)lw + byte);
        *(short8*)&B2[((size_t)e * DIM + d0 + d) * HP2 + h0 + kc] = vv;
    }
}

// ---------------------------------------------------------------------------
// GEMM1 (MFMA, swizzled LDS): h[slot,:] = silu(Xe@Wg)*(Xe@Wu), 128x128x32
// 2-phase static double-buffer (at its structural ceiling, m233/m248)
// + XCD-chunked block swizzle.
// ---------------------------------------------------------------------------
__global__ __launch_bounds__(256, 2) void gemm1_kernel(
    const unsigned short* __restrict__ xb, const unsigned short* __restrict__ B1,
    const int* __restrict__ counts, const int* __restrict__ offs,
    const int* __restrict__ lists, unsigned short* __restrict__ h)
{
    const int e = blockIdx.z;
    const int cnt = counts[e];
    int wg = blockIdx.x + 22 * blockIdx.y;
    wg = (wg & 7) * 88 + (wg >> 3);
    const int by = wg & 31;          // row-block (fastest within XCD chunk)
    const int bx = wg >> 5;          // n-block
    const int row0 = by * 128;
    if (row0 >= cnt) return;
    const int off = offs[e];
    const int n0 = bx * 128;

    __shared__ unsigned short s1[24576];   // 48 KB: 2 x (A | Bg | Bu)
    __shared__ int s_pr[128];

    const int tid = threadIdx.x;
    const int w = tid >> 6, lane = tid & 63;
    if (tid < 128) {
        const int r = row0 + tid;
        s_pr[tid] = (r < cnt) ? lists[e * T_TOK + r] : -1;
    }
    __syncthreads();

    // staging: row rA, swizzled source k-block
    const int rA = tid >> 2, kb = tid & 3;
    const int kbs = (kb ^ ((rA >> 1) & 3)) * 8;   // elems
    const int pr0 = s_pr[rA], pr1 = s_pr[rA + 64];
    const unsigned short* agp0 = xb + (size_t)(max(pr0, 0) >> 1) * DIM + kbs;
    const unsigned short* agp1 = xb + (size_t)(max(pr1, 0) >> 1) * DIM + kbs;
    const unsigned short* bgp0 = B1 + ((size_t)e * NB1 + n0 + rA) * DIM + kbs;
    const unsigned short* bgp1 = bgp0 + (size_t)64 * DIM;
    const unsigned short* bup0 = B1 + ((size_t)e * NB1 + HP2 + n0 + rA) * DIM + kbs;
    const unsigned short* bup1 = bup0 + (size_t)64 * DIM;

    char* const s1b = (char*)s1;
    const int sw = w * 1024;

    f32x4 accg[4][4], accu[4][4];
    #pragma unroll
    for (int i = 0; i < 4; ++i)
        #pragma unroll
        for (int j = 0; j < 4; ++j) { accg[i][j] = (f32x4)0.f; accu[i][j] = (f32x4)0.f; }

    const int wm = w & 1, wn = w >> 1;
    const int fm = lane & 15, fq = lane >> 4;
    const int kq = (fq ^ ((fm >> 1) & 3)) * 8;    // swizzled fragment k-offset

    auto STAGE = [&](char* base, int k0) {
        load_lds16(agp0 + k0, base + sw);
        load_lds16(agp1 + k0, base + 4096 + sw);
        load_lds16(bgp0 + k0, base + 8192 + sw);
        load_lds16(bgp1 + k0, base + 12288 + sw);
        load_lds16(bup0 + k0, base + 16384 + sw);
        load_lds16(bup1 + k0, base + 20480 + sw);
    };
    auto COMPUTE = [&](const unsigned short* bufA) {
        const unsigned short* bufG = bufA + 4096;
        const unsigned short* bufU = bufA + 8192;
        short8 a[4], bg[4], bu[4];
        #pragma unroll
        for (int i = 0; i < 4; ++i) {
            a[i]  = *(const short8*)&bufA[(wm * 64 + i * 16 + fm) * 32 + kq];
            bg[i] = *(const short8*)&bufG[(wn * 64 + i * 16 + fm) * 32 + kq];
            bu[i] = *(const short8*)&bufU[(wn * 64 + i * 16 + fm) * 32 + kq];
        }
        __builtin_amdgcn_s_setprio(1);
        #pragma unroll
        for (int i = 0; i < 4; ++i)
            #pragma unroll
            for (int j = 0; j < 4; ++j) {
                accg[i][j] = __builtin_amdgcn_mfma_f32_16x16x32_bf16(a[i], bg[j], accg[i][j], 0, 0, 0);
                accu[i][j] = __builtin_amdgcn_mfma_f32_16x16x32_bf16(a[i], bu[j], accu[i][j], 0, 0, 0);
            }
        __builtin_amdgcn_s_setprio(0);
    };

    STAGE(s1b, 0);
    __syncthreads();
    #pragma unroll 1
    for (int g = 0; g < 16; ++g) {
        STAGE(s1b + 24576, g * 64 + 32);
        COMPUTE(s1);
        __syncthreads();
        if (g < 15) STAGE(s1b, g * 64 + 64);
        COMPUTE(s1 + 12288);
        __syncthreads();
    }

    // epilogue: silu(g)*u -> LDS bounce, 16B stores
    unsigned short* wbuf = s1 + w * 1152;   // 2304 B per wave, per-wave private
    const int rrow = lane >> 2, cq = (lane & 3) * 16;
    #pragma unroll
    for (int i = 0; i < 4; ++i) {
        #pragma unroll
        for (int j = 0; j < 4; ++j)
            #pragma unroll
            for (int reg = 0; reg < 4; ++reg) {
                const float g = accg[i][j][reg];
                const float u = accu[i][j][reg];
                const float s = g / (1.f + __expf(-g));
                wbuf[(fq * 4 + reg) * 72 + j * 16 + fm] = f2bf(s * u);
            }
        const int rl = wm * 64 + i * 16 + rrow;
        if (row0 + rl < cnt) {
            unsigned short* dst = h + (size_t)(off + row0 + rl) * HP2 + n0 + wn * 64 + cq;
            const short8 v0 = *(const short8*)&wbuf[rrow * 72 + cq];
            const short8 v1 = *(const short8*)&wbuf[rrow * 72 + cq + 8];
            *(short8*)dst = v0;
            *(short8*)(dst + 8) = v1;
        }
    }
}

// ---------------------------------------------------------------------------
// GEMM2 (MFMA, swizzled LDS): op[pr,:] = h_slot @ Wd, 128x128, K=2816.
// 3-buffer depth-2 counted-vmcnt pipeline (r1 topology, STATIC buffers:
// loop unrolled by 3 so all LDS addresses are compile-time; no runtime
// rotation, no branches in the steady loop). One raw s_barrier per K-step,
// vmcnt(4) keeps the prefetched tile's 4 loads in flight across it.
// ---------------------------------------------------------------------------
__global__ __launch_bounds__(256, 2) void gemm2_kernel(
    const unsigned short* __restrict__ h, const unsigned short* __restrict__ B2,
    const int* __restrict__ counts, const int* __restrict__ offs,
    const int* __restrict__ lists, unsigned short* __restrict__ op)
{
    const int e = blockIdx.z;
    const int cnt = counts[e];
    int wg = blockIdx.x + 8 * blockIdx.y;
    wg = (wg & 7) * 32 + (wg >> 3);
    const int by = wg & 31;          // row-block (fastest)
    const int bx = wg >> 5;          // n-block
    const int row0 = by * 128;
    if (row0 >= cnt) return;
    const int off = offs[e];
    const int n0 = bx * 128;

    __shared__ unsigned short s2[24576];   // 48 KB: 3 x (A | B) 16 KB buffers
    __shared__ int s_pr[128];

    const int tid = threadIdx.x;
    const int w = tid >> 6, lane = tid & 63;
    if (tid < 128) {
        const int r = row0 + tid;
        s_pr[tid] = (r < cnt) ? lists[e * T_TOK + r] : -1;
    }
    __syncthreads();

    const int rA = tid >> 2, kb = tid & 3;
    const int kbs = (kb ^ ((rA >> 1) & 3)) * 8;
    const unsigned short* agp0 = h + (size_t)(off + row0 + rA) * HP2 + kbs;
    const unsigned short* agp1 = agp0 + (size_t)64 * HP2;
    const unsigned short* bp0 = B2 + ((size_t)e * DIM + n0 + rA) * HP2 + kbs;
    const unsigned short* bp1 = bp0 + (size_t)64 * HP2;

    char* const s2b = (char*)s2;
    const int sw = w * 1024;

    f32x4 acc[4][4];
    #pragma unroll
    for (int i = 0; i < 4; ++i)
        #pragma unroll
        for (int j = 0; j < 4; ++j) acc[i][j] = (f32x4)0.f;

    const int wm = w & 1, wn = w >> 1;
    const int fm = lane & 15, fq = lane >> 4;
    const int kq = (fq ^ ((fm >> 1) & 3)) * 8;

    auto STAGE = [&](char* base, int k0) {
        load_lds16(agp0 + k0, base + sw);
        load_lds16(agp1 + k0, base + 4096 + sw);
        load_lds16(bp0 + k0,  base + 8192 + sw);
        load_lds16(bp1 + k0,  base + 12288 + sw);
    };
    auto COMPUTE = [&](const unsigned short* bufA) {
        const unsigned short* bufB = bufA + 4096;
        short8 a[4], bb[4];
        #pragma unroll
        for (int i = 0; i < 4; ++i) {
            a[i]  = *(const short8*)&bufA[(wm * 64 + i * 16 + fm) * 32 + kq];
            bb[i] = *(const short8*)&bufB[(wn * 64 + i * 16 + fm) * 32 + kq];
        }
        __builtin_amdgcn_s_setprio(1);
        #pragma unroll
        for (int i = 0; i < 4; ++i)
            #pragma unroll
            for (int j = 0; j < 4; ++j)
                acc[i][j] = __builtin_amdgcn_mfma_f32_16x16x32_bf16(a[i], bb[j], acc[i][j], 0, 0, 0);
        __builtin_amdgcn_s_setprio(0);
    };

    // prologue: tiles 0,1 in flight; wait tile0 only (tile1 stays in flight)
    STAGE(s2b, 0);
    STAGE(s2b + 16384, 32);
    asm volatile("s_waitcnt vmcnt(4)" ::: "memory");
    __builtin_amdgcn_s_barrier();

    // steady loop: 28 iterations x 3 K-steps (kt = 0..83); each body:
    // STAGE(kt+2) -> COMPUTE(kt) -> vmcnt(4) -> barrier.  All buffer
    // addresses static (kt%3 fixed per body).
    #pragma unroll 1
    for (int base = 0; base < 84; base += 3) {
        const int k2 = (base + 2) * 32;
        STAGE(s2b + 32768, k2);            // tile kt+2 -> buf2
        COMPUTE(s2);                       // buf0
        asm volatile("s_waitcnt vmcnt(4)" ::: "memory");
        __builtin_amdgcn_s_barrier();

        STAGE(s2b, k2 + 32);               // -> buf0
        COMPUTE(s2 + 8192);                // buf1
        asm volatile("s_waitcnt vmcnt(4)" ::: "memory");
        __builtin_amdgcn_s_barrier();

        STAGE(s2b + 16384, k2 + 64);       // -> buf1
        COMPUTE(s2 + 16384);               // buf2
        asm volatile("s_waitcnt vmcnt(4)" ::: "memory");
        __builtin_amdgcn_s_barrier();
    }
    // tail: kt = 84..87 (tiles 84..87; stage 86,87 then drain)
    STAGE(s2b + 32768, 86 * 32);           // -> buf2
    COMPUTE(s2);                           // buf0 (tile 84)
    asm volatile("s_waitcnt vmcnt(4)" ::: "memory");
    __builtin_amdgcn_s_barrier();

    STAGE(s2b, 87 * 32);                   // -> buf0
    COMPUTE(s2 + 8192);                    // buf1 (tile 85)
    asm volatile("s_waitcnt vmcnt(4)" ::: "memory");
    __builtin_amdgcn_s_barrier();

    COMPUTE(s2 + 16384);                   // buf2 (tile 86)
    asm volatile("s_waitcnt vmcnt(0)" ::: "memory");
    __builtin_amdgcn_s_barrier();

    COMPUTE(s2);                           // buf0 (tile 87)
    __builtin_amdgcn_s_barrier();

    // epilogue: LDS bounce (buf0 region, all reads barrier'd), scatter rows
    unsigned short* wbuf = s2 + w * 1152;
    const int rrow = lane >> 2, cq = (lane & 3) * 16;
    #pragma unroll
    for (int i = 0; i < 4; ++i) {
        #pragma unroll
        for (int j = 0; j < 4; ++j)
            #pragma unroll
            for (int reg = 0; reg < 4; ++reg)
                wbuf[(fq * 4 + reg) * 72 + j * 16 + fm] = f2bf(acc[i][j][reg]);
        const int rl = wm * 64 + i * 16 + rrow;
        const int pr = s_pr[rl];
        if (pr >= 0) {
            unsigned short* dst = op + (size_t)pr * DIM + n0 + wn * 64 + cq;
            const short8 v0 = *(const short8*)&wbuf[rrow * 72 + cq];
            const short8 v1 = *(const short8*)&wbuf[rrow * 72 + cq + 8];
            *(short8*)dst = v0;
            *(short8*)(dst + 8) = v1;
        }
    }
}

// ---------------------------------------------------------------------------
// Combine: out[t] = w0*op[2t] + w1*op[2t+1]  (op bf16 -> out f32)
// ---------------------------------------------------------------------------
__global__ __launch_bounds__(256) void combine_kernel(
    const unsigned short* __restrict__ op, const float* __restrict__ pairw,
    float* __restrict__ out)
{
    const int f = blockIdx.x * 256 + threadIdx.x;   // over T*D/4
    const int t = f >> 8;
    const int c = f & 255;
    const float w0 = pairw[2 * t], w1 = pairw[2 * t + 1];
    const us4 a = ((const us4*)op)[(size_t)(2 * t) * (DIM / 4) + c];
    const us4 b = ((const us4*)op)[(size_t)(2 * t + 1) * (DIM / 4) + c];
    float4 r;
    r.x = w0 * __uint_as_float((unsigned)a.x << 16) + w1 * __uint_as_float((unsigned)b.x << 16);
    r.y = w0 * __uint_as_float((unsigned)a.y << 16) + w1 * __uint_as_float((unsigned)b.y << 16);
    r.z = w0 * __uint_as_float((unsigned)a.z << 16) + w1 * __uint_as_float((unsigned)b.z << 16);
    r.w = w0 * __uint_as_float((unsigned)a.w << 16) + w1 * __uint_as_float((unsigned)b.w << 16);
    ((float4*)out)[f] = r;
}

extern "C" void kernel_launch(void* const* d_in, const int* in_sizes, int n_in,
                              void* d_out, int out_size, void* d_ws, size_t ws_size,
                              hipStream_t stream)
{
    const float* x  = (const float*)d_in[0];
    const float* rw = (const float*)d_in[1];
    const float* wg = (const float*)d_in[2];
    const float* wu = (const float*)d_in[3];
    const float* wd = (const float*)d_in[4];
    float* out = (float*)d_out;
    char* ws = (char*)d_ws;

    int*   counts = (int*)(ws + OFF_CNT);
    float* usage  = (float*)(ws + OFF_USE);
    float* zacc   = (float*)(ws + OFF_Z);
    int*   offs   = (int*)(ws + OFF_OFFS);
    int*   lists  = (int*)(ws + OFF_LIST);
    float* pairw  = (float*)(ws + OFF_PAIRW);
    unsigned short* xb  = (unsigned short*)(ws + OFF_XB);
    unsigned short* hb  = (unsigned short*)(ws + OFF_H);
    unsigned short* B2  = (unsigned short*)(ws + OFF_B2);
    unsigned short* B1  = (unsigned short*)(ws + OFF_B1);
    unsigned short* op  = (unsigned short*)(ws + OFF_OP);

    hipMemsetAsync(ws, 0, 128, stream);

    router_kernel<<<T_TOK / 4, 256, 0, stream>>>(x, rw, counts, usage, zacc, lists, pairw, xb);
    finalize_kernel<<<1, 64, 0, stream>>>(counts, usage, zacc, offs, out);

    conv_w1_kernel<<<dim3(HP2 / 128, DIM / 128, NEXP), 256, 0, stream>>>(wg, wu, B1);
    conv_w2_kernel<<<dim3(HP2 / 128, DIM / 128, NEXP), 256, 0, stream>>>(wd, B2);

    gemm1_kernel<<<dim3(HP2 / 128, T_TOK / 128, NEXP), 256, 0, stream>>>(xb, B1, counts, offs, lists, hb);
    gemm2_kernel<<<dim3(DIM / 128, T_TOK / 128, NEXP), 256, 0, stream>>>(hb, B2, counts, offs, lists, op);

    combine_kernel<<<(T_TOK * DIM / 4) / 256, 256, 0, stream>>>(op, pairw, out);
}

// Round 8
// 535.859 us; speedup vs baseline: 1.1825x; 1.1825x over previous
//
#include <hip/hip_runtime.h>
#include <cstdint>
#include <cstddef>

// Problem constants
#define T_TOK 4096
#define DIM   1024
#define NEXP  8
#define HID   2730
#define HP2   2816          // hidden padded to 88*32 = 22*128
#define NB1   5632          // 2*HP2 rows (gate || up) in transposed B1
#define NPAIR (T_TOK*2)

typedef __attribute__((ext_vector_type(8))) short short8;
typedef __attribute__((ext_vector_type(4))) float f32x4;

// ws layout (bytes)
#define OFF_CNT   0UL
#define OFF_USE   64UL
#define OFF_Z     96UL
#define OFF_OFFS  160UL                                   // 8 ints (prefix offsets)
#define OFF_LIST  256UL                                   // 8*4096 ints
#define OFF_PAIRW 131328UL                                // 8192 floats
#define OFF_XB    164096UL                                // 4096*1024 bf16
#define OFF_H     (OFF_XB + 8388608UL)                    // 8192*2816 bf16 (slot-compacted)
#define OFF_B2    (OFF_H + 46137344UL)                    // 8*1024*2816 bf16
#define OFF_B1    (OFF_B2 + 46137344UL)                   // 8*5632*1024 bf16
#define OFF_OP    OFF_B1                                  // overlay: 8192*1024 bf16 (B1 dead after gemm1)

__device__ __forceinline__ unsigned short f2bf(float f) {
    unsigned u = __float_as_uint(f);
    return (unsigned short)((u + 0x7FFFu + ((u >> 16) & 1u)) >> 16);
}

__device__ __forceinline__ unsigned pack2(float a, float b) {
    return (unsigned)f2bf(a) | ((unsigned)f2bf(b) << 16);
}

__device__ __forceinline__ void load_lds16(const void* g, void* l) {
    __builtin_amdgcn_global_load_lds(
        (const __attribute__((address_space(1))) void*)g,
        (__attribute__((address_space(3))) void*)l, 16, 0, 0);
}

struct __align__(8) us4 { unsigned short x, y, z, w; };
struct __align__(8) u32x2 { unsigned x, y; };

// ---------------------------------------------------------------------------
// Router v2 (fp32, exact) + x->bf16 fused. 16 tokens/block; counts & lists
// aggregated in LDS -> 8 global atomics/block (was 32+) and coalesced list
// writes. List order within an expert is arbitrary (rows are order-free).
// ---------------------------------------------------------------------------
__global__ __launch_bounds__(256) void router_kernel(
    const float* __restrict__ x, const float* __restrict__ rw,
    int* __restrict__ counts, float* __restrict__ usage, float* __restrict__ zacc,
    int* __restrict__ lists, float* __restrict__ pairw,
    unsigned short* __restrict__ xb)
{
    __shared__ float s_rw[NEXP][DIM];   // transposed: lane-stride-1 reads
    __shared__ float s_use[NEXP];
    __shared__ float s_z;
    __shared__ int   s_cnt[NEXP];
    __shared__ int   s_base[NEXP];
    __shared__ int   s_items[NEXP][32];   // max 16 tokens * 2 slots
    const int tid = threadIdx.x;
    for (int i = tid; i < DIM * NEXP; i += 256) s_rw[i & 7][i >> 3] = rw[i];
    if (tid < NEXP) { s_use[tid] = 0.f; s_cnt[tid] = 0; }
    if (tid == NEXP) s_z = 0.f;
    __syncthreads();

    const int wave = tid >> 6, lane = tid & 63;

    #pragma unroll 1
    for (int it = 0; it < 4; ++it) {
        const int t = blockIdx.x * 16 + wave * 4 + it;
        float acc[NEXP];
        #pragma unroll
        for (int e = 0; e < NEXP; ++e) acc[e] = 0.f;
        #pragma unroll
        for (int j = 0; j < DIM / 64; ++j) {
            const int d = j * 64 + lane;
            const float xv = x[(size_t)t * DIM + d];
            xb[(size_t)t * DIM + d] = f2bf(xv);
            #pragma unroll
            for (int e = 0; e < NEXP; ++e) acc[e] = fmaf(xv, s_rw[e][d], acc[e]);
        }
        #pragma unroll
        for (int e = 0; e < NEXP; ++e) {
            float v = acc[e];
            for (int off = 32; off > 0; off >>= 1) v += __shfl_down(v, off, 64);
            acc[e] = v;
        }
        if (lane == 0) {
            float l[NEXP];
            #pragma unroll
            for (int e = 0; e < NEXP; ++e) l[e] = acc[e];
            float m = l[0];
            #pragma unroll
            for (int e = 1; e < NEXP; ++e) m = fmaxf(m, l[e]);
            float se = 0.f;
            #pragma unroll
            for (int e = 0; e < NEXP; ++e) se += __expf(l[e] - m);
            const float lse = m + __logf(se);
            #pragma unroll
            for (int e = 0; e < NEXP; ++e) atomicAdd(&s_use[e], __expf(l[e] - m) / se);
            atomicAdd(&s_z, lse * lse);
            int i0 = 0; float l0 = l[0];
            #pragma unroll
            for (int e = 1; e < NEXP; ++e) if (l[e] > l0) { l0 = l[e]; i0 = e; }
            int i1 = -1; float l1 = -1e30f;
            #pragma unroll
            for (int e = 0; e < NEXP; ++e) if (e != i0 && l[e] > l1) { l1 = l[e]; i1 = e; }
            const float p0 = 1.f / (1.f + __expf(l1 - l0));
            const float p1 = 1.f - p0;
            const int pos0 = atomicAdd(&s_cnt[i0], 1);
            s_items[i0][pos0] = (t << 1);
            const int pos1 = atomicAdd(&s_cnt[i1], 1);
            s_items[i1][pos1] = (t << 1) | 1;
            pairw[2 * t]     = p0;
            pairw[2 * t + 1] = p1;
        }
    }
    __syncthreads();
    if (tid < NEXP) {
        s_base[tid] = atomicAdd(&counts[tid], s_cnt[tid]);
        atomicAdd(&usage[tid], s_use[tid]);
    }
    if (tid == NEXP) atomicAdd(zacc, s_z);
    __syncthreads();
    // coalesced list flush: thread f covers (expert f>>5, slot f&31)
    {
        const int e = tid >> 5, idx = tid & 31;
        if (idx < s_cnt[e]) lists[e * T_TOK + s_base[e] + idx] = s_items[e][idx];
    }
}

// ---------------------------------------------------------------------------
// Fused weight conversion (v4 transposes) + finalize folded into block 0.
// z in [0,8): conv_w1 for expert z;  z in [8,16): conv_w2 for expert z-8.
// ---------------------------------------------------------------------------
__global__ __launch_bounds__(256) void conv_kernel(
    const float* __restrict__ wg, const float* __restrict__ wu,
    const float* __restrict__ wd,
    unsigned short* __restrict__ B1, unsigned short* __restrict__ B2,
    const int* __restrict__ counts, const float* __restrict__ usage,
    const float* __restrict__ zacc, int* __restrict__ offs,
    float* __restrict__ out)
{
    __shared__ unsigned short lga[128 * 128];   // 32 KB
    __shared__ unsigned short lub[128 * 128];   // 32 KB (w2 path uses lga only)
    const int tid = threadIdx.x;

    // finalize (counts are complete: stream-ordered after router)
    if (blockIdx.x == 0 && blockIdx.y == 0 && blockIdx.z == 0 && tid == 0) {
        int o = 0;
        for (int e = 0; e < NEXP; ++e) { offs[e] = o; o += counts[e]; }
        float s = 0.f;
        for (int e = 0; e < NEXP; ++e) {
            const float u = usage[e] / (float)T_TOK;
            s += u * u;
        }
        out[(size_t)T_TOK * DIM]     = (float)NEXP * s;
        out[(size_t)T_TOK * DIM + 1] = zacc[0] / (float)T_TOK;
    }

    const int e = blockIdx.z & 7;
    if (blockIdx.z < 8) {
        // ---- conv_w1: B1[e][h][k] (gate) / B1[e][HP2+h][k] (up) ----
        const int h0 = blockIdx.x * 128;  // n dim (HID, padded to HP2)
        const int k0 = blockIdx.y * 128;  // k dim (DIM)
        const size_t wb = (size_t)e * DIM * HID;
        const int hu = (tid & 31) * 4;
        const int kg = tid >> 5;
        const bool full = (h0 + 128 <= HID);

        #pragma unroll
        for (int uu = 0; uu < 4; ++uu) {
            const int kk = (kg * 4 + uu) * 4;
            f32x4 g[4], u[4];
            if (full) {
                #pragma unroll
                for (int j = 0; j < 4; ++j) {
                    const size_t src = wb + (size_t)(k0 + kk + j) * HID + h0 + hu;
                    g[j] = *(const f32x4*)&wg[src];
                    u[j] = *(const f32x4*)&wu[src];
                }
            } else {
                #pragma unroll
                for (int j = 0; j < 4; ++j) {
                    #pragma unroll
                    for (int c = 0; c < 4; ++c) {
                        const int hh = h0 + hu + c;
                        float gv = 0.f, uv = 0.f;
                        if (hh < HID) {
                            const size_t src = wb + (size_t)(k0 + kk + j) * HID + hh;
                            gv = wg[src]; uv = wu[src];
                        }
                        g[j][c] = gv; u[j][c] = uv;
                    }
                }
            }
            #pragma unroll
            for (int i = 0; i < 4; ++i) {
                const int h = hu + i;
                const int byte = (((h * 128 + kk) * 2) ^ ((h & 15) << 4));
                u32x2 vg; vg.x = pack2(g[0][i], g[1][i]); vg.y = pack2(g[2][i], g[3][i]);
                u32x2 vu; vu.x = pack2(u[0][i], u[1][i]); vu.y = pack2(u[2][i], u[3][i]);
                *(u32x2*)((char*)lga + byte) = vg;
                *(u32x2*)((char*)lub + byte) = vu;
            }
        }
        __syncthreads();

        const int kc  = (tid & 15) * 8;
        const int hrb = tid >> 4;
        #pragma unroll
        for (int wo = 0; wo < 8; ++wo) {
            const int h = hrb + wo * 16;
            const int byte = (((h * 128 + kc) * 2) ^ ((h & 15) << 4));
            const short8 vg = *(const short8*)((const char*)lga + byte);
            const short8 vu = *(const short8*)((const char*)lub + byte);
            *(short8*)&B1[((size_t)e * NB1 + h0 + h) * DIM + k0 + kc] = vg;
            *(short8*)&B1[((size_t)e * NB1 + HP2 + h0 + h) * DIM + k0 + kc] = vu;
        }
    } else {
        // ---- conv_w2: B2[e][d][kh]; k-rows in [HID,HP2) zeroed ----
        const int h0 = blockIdx.x * 128;  // k dim of B2 (= wd row)
        const int d0 = blockIdx.y * 128;  // n dim (= wd col)
        const size_t wb = (size_t)e * HID * DIM;
        const int du = (tid & 31) * 4;
        const int kg = tid >> 5;

        #pragma unroll
        for (int uu = 0; uu < 4; ++uu) {
            const int kk = (kg * 4 + uu) * 4;
            f32x4 v[4];
            #pragma unroll
            for (int j = 0; j < 4; ++j) {
                const int hh = h0 + kk + j;
                if (hh < HID) v[j] = *(const f32x4*)&wd[wb + (size_t)hh * DIM + d0 + du];
                else          v[j] = (f32x4)0.f;
            }
            #pragma unroll
            for (int i = 0; i < 4; ++i) {
                const int d = du + i;
                const int byte = (((d * 128 + kk) * 2) ^ ((d & 15) << 4));
                u32x2 vv; vv.x = pack2(v[0][i], v[1][i]); vv.y = pack2(v[2][i], v[3][i]);
                *(u32x2*)((char*)lga + byte) = vv;
            }
        }
        __syncthreads();

        const int kc  = (tid & 15) * 8;
        const int drb = tid >> 4;
        #pragma unroll
        for (int wo = 0; wo < 8; ++wo) {
            const int d = drb + wo * 16;
            const int byte = (((d * 128 + kc) * 2) ^ ((d & 15) << 4));
            const short8 vv = *(const short8*)((const char*)lga + byte);
            *(short8*)&B2[((size_t)e * DIM + d0 + d) * HP2 + h0 + kc] = vv;
        }
    }
}

// ---------------------------------------------------------------------------
// GEMM1 (MFMA, swizzled LDS): h[slot,:] = silu(Xe@Wg)*(Xe@Wu), 128x128x32
// 2-phase static double-buffer (at its structural ceiling, m233/m248)
// + XCD-chunked block swizzle.
// ---------------------------------------------------------------------------
__global__ __launch_bounds__(256, 2) void gemm1_kernel(
    const unsigned short* __restrict__ xb, const unsigned short* __restrict__ B1,
    const int* __restrict__ counts, const int* __restrict__ offs,
    const int* __restrict__ lists, unsigned short* __restrict__ h)
{
    const int e = blockIdx.z;
    const int cnt = counts[e];
    int wg = blockIdx.x + 22 * blockIdx.y;
    wg = (wg & 7) * 88 + (wg >> 3);
    const int by = wg & 31;          // row-block (fastest within XCD chunk)
    const int bx = wg >> 5;          // n-block
    const int row0 = by * 128;
    if (row0 >= cnt) return;
    const int off = offs[e];
    const int n0 = bx * 128;

    __shared__ unsigned short s1[24576];   // 48 KB: 2 x (A | Bg | Bu)
    __shared__ int s_pr[128];

    const int tid = threadIdx.x;
    const int w = tid >> 6, lane = tid & 63;
    if (tid < 128) {
        const int r = row0 + tid;
        s_pr[tid] = (r < cnt) ? lists[e * T_TOK + r] : -1;
    }
    __syncthreads();

    // staging: row rA, swizzled source k-block
    const int rA = tid >> 2, kb = tid & 3;
    const int kbs = (kb ^ ((rA >> 1) & 3)) * 8;   // elems
    const int pr0 = s_pr[rA], pr1 = s_pr[rA + 64];
    const unsigned short* agp0 = xb + (size_t)(max(pr0, 0) >> 1) * DIM + kbs;
    const unsigned short* agp1 = xb + (size_t)(max(pr1, 0) >> 1) * DIM + kbs;
    const unsigned short* bgp0 = B1 + ((size_t)e * NB1 + n0 + rA) * DIM + kbs;
    const unsigned short* bgp1 = bgp0 + (size_t)64 * DIM;
    const unsigned short* bup0 = B1 + ((size_t)e * NB1 + HP2 + n0 + rA) * DIM + kbs;
    const unsigned short* bup1 = bup0 + (size_t)64 * DIM;

    char* const s1b = (char*)s1;
    const int sw = w * 1024;

    f32x4 accg[4][4], accu[4][4];
    #pragma unroll
    for (int i = 0; i < 4; ++i)
        #pragma unroll
        for (int j = 0; j < 4; ++j) { accg[i][j] = (f32x4)0.f; accu[i][j] = (f32x4)0.f; }

    const int wm = w & 1, wn = w >> 1;
    const int fm = lane & 15, fq = lane >> 4;
    const int kq = (fq ^ ((fm >> 1) & 3)) * 8;    // swizzled fragment k-offset

    auto STAGE = [&](char* base, int k0) {
        load_lds16(agp0 + k0, base + sw);
        load_lds16(agp1 + k0, base + 4096 + sw);
        load_lds16(bgp0 + k0, base + 8192 + sw);
        load_lds16(bgp1 + k0, base + 12288 + sw);
        load_lds16(bup0 + k0, base + 16384 + sw);
        load_lds16(bup1 + k0, base + 20480 + sw);
    };
    auto COMPUTE = [&](const unsigned short* bufA) {
        const unsigned short* bufG = bufA + 4096;
        const unsigned short* bufU = bufA + 8192;
        short8 a[4], bg[4], bu[4];
        #pragma unroll
        for (int i = 0; i < 4; ++i) {
            a[i]  = *(const short8*)&bufA[(wm * 64 + i * 16 + fm) * 32 + kq];
            bg[i] = *(const short8*)&bufG[(wn * 64 + i * 16 + fm) * 32 + kq];
            bu[i] = *(const short8*)&bufU[(wn * 64 + i * 16 + fm) * 32 + kq];
        }
        __builtin_amdgcn_s_setprio(1);
        #pragma unroll
        for (int i = 0; i < 4; ++i)
            #pragma unroll
            for (int j = 0; j < 4; ++j) {
                accg[i][j] = __builtin_amdgcn_mfma_f32_16x16x32_bf16(a[i], bg[j], accg[i][j], 0, 0, 0);
                accu[i][j] = __builtin_amdgcn_mfma_f32_16x16x32_bf16(a[i], bu[j], accu[i][j], 0, 0, 0);
            }
        __builtin_amdgcn_s_setprio(0);
    };

    STAGE(s1b, 0);
    __syncthreads();
    #pragma unroll 1
    for (int g = 0; g < 16; ++g) {
        STAGE(s1b + 24576, g * 64 + 32);
        COMPUTE(s1);
        __syncthreads();
        if (g < 15) STAGE(s1b, g * 64 + 64);
        COMPUTE(s1 + 12288);
        __syncthreads();
    }

    // epilogue: silu(g)*u -> LDS bounce, 16B stores
    unsigned short* wbuf = s1 + w * 1152;   // 2304 B per wave, per-wave private
    const int rrow = lane >> 2, cq = (lane & 3) * 16;
    #pragma unroll
    for (int i = 0; i < 4; ++i) {
        #pragma unroll
        for (int j = 0; j < 4; ++j)
            #pragma unroll
            for (int reg = 0; reg < 4; ++reg) {
                const float g = accg[i][j][reg];
                const float u = accu[i][j][reg];
                const float s = g / (1.f + __expf(-g));
                wbuf[(fq * 4 + reg) * 72 + j * 16 + fm] = f2bf(s * u);
            }
        const int rl = wm * 64 + i * 16 + rrow;
        if (row0 + rl < cnt) {
            unsigned short* dst = h + (size_t)(off + row0 + rl) * HP2 + n0 + wn * 64 + cq;
            const short8 v0 = *(const short8*)&wbuf[rrow * 72 + cq];
            const short8 v1 = *(const short8*)&wbuf[rrow * 72 + cq + 8];
            *(short8*)dst = v0;
            *(short8*)(dst + 8) = v1;
        }
    }
}

// ---------------------------------------------------------------------------
// GEMM2 (MFMA, swizzled LDS): op[pr,:] = h_slot @ Wd, 128x128, K=2816.
// BK=64 per barrier, 2-phase static double-buffer + XCD swizzle (r6 version).
// ---------------------------------------------------------------------------
__global__ __launch_bounds__(256, 2) void gemm2_kernel(
    const unsigned short* __restrict__ h, const unsigned short* __restrict__ B2,
    const int* __restrict__ counts, const int* __restrict__ offs,
    const int* __restrict__ lists, unsigned short* __restrict__ op)
{
    const int e = blockIdx.z;
    const int cnt = counts[e];
    int wg = blockIdx.x + 8 * blockIdx.y;
    wg = (wg & 7) * 32 + (wg >> 3);
    const int by = wg & 31;          // row-block (fastest)
    const int bx = wg >> 5;          // n-block
    const int row0 = by * 128;
    if (row0 >= cnt) return;
    const int off = offs[e];
    const int n0 = bx * 128;

    __shared__ unsigned short s2[32768];   // 64 KB: 2 x (A0|A1|B0|B1), 16 KB subtiles
    __shared__ int s_pr[128];

    const int tid = threadIdx.x;
    const int w = tid >> 6, lane = tid & 63;
    if (tid < 128) {
        const int r = row0 + tid;
        s_pr[tid] = (r < cnt) ? lists[e * T_TOK + r] : -1;
    }
    __syncthreads();

    const int rA = tid >> 2, kb = tid & 3;
    const int kbs = (kb ^ ((rA >> 1) & 3)) * 8;
    const unsigned short* agp0 = h + (size_t)(off + row0 + rA) * HP2 + kbs;
    const unsigned short* agp1 = agp0 + (size_t)64 * HP2;
    const unsigned short* bp0 = B2 + ((size_t)e * DIM + n0 + rA) * HP2 + kbs;
    const unsigned short* bp1 = bp0 + (size_t)64 * HP2;

    char* const s2b = (char*)s2;
    const int sw = w * 1024;

    f32x4 acc[4][4];
    #pragma unroll
    for (int i = 0; i < 4; ++i)
        #pragma unroll
        for (int j = 0; j < 4; ++j) acc[i][j] = (f32x4)0.f;

    const int wm = w & 1, wn = w >> 1;
    const int fm = lane & 15, fq = lane >> 4;
    const int kq = (fq ^ ((fm >> 1) & 3)) * 8;

    auto STAGE = [&](char* base, int k0) {
        load_lds16(agp0 + k0,      base + sw);
        load_lds16(agp1 + k0,      base + 4096 + sw);
        load_lds16(agp0 + k0 + 32, base + 8192 + sw);
        load_lds16(agp1 + k0 + 32, base + 12288 + sw);
        load_lds16(bp0 + k0,       base + 16384 + sw);
        load_lds16(bp1 + k0,       base + 20480 + sw);
        load_lds16(bp0 + k0 + 32,  base + 24576 + sw);
        load_lds16(bp1 + k0 + 32,  base + 28672 + sw);
    };
    auto COMPUTE = [&](const unsigned short* buf) {
        #pragma unroll
        for (int hh = 0; hh < 2; ++hh) {
            const unsigned short* bufA = buf + hh * 4096;
            const unsigned short* bufB = buf + 8192 + hh * 4096;
            short8 a[4], bb[4];
            #pragma unroll
            for (int i = 0; i < 4; ++i) {
                a[i]  = *(const short8*)&bufA[(wm * 64 + i * 16 + fm) * 32 + kq];
                bb[i] = *(const short8*)&bufB[(wn * 64 + i * 16 + fm) * 32 + kq];
            }
            __builtin_amdgcn_s_setprio(1);
            #pragma unroll
            for (int i = 0; i < 4; ++i)
                #pragma unroll
                for (int j = 0; j < 4; ++j)
                    acc[i][j] = __builtin_amdgcn_mfma_f32_16x16x32_bf16(a[i], bb[j], acc[i][j], 0, 0, 0);
            __builtin_amdgcn_s_setprio(0);
        }
    };

    STAGE(s2b, 0);
    __syncthreads();
    #pragma unroll 1
    for (int g = 0; g < 22; ++g) {
        STAGE(s2b + 32768, g * 128 + 64);   // max start 2752, reads to 2816 = HP2
        COMPUTE(s2);
        __syncthreads();
        if (g < 21) STAGE(s2b, g * 128 + 128);
        COMPUTE(s2 + 16384);
        __syncthreads();
    }

    // epilogue: LDS bounce, scatter rows by pair id (bf16 op)
    unsigned short* wbuf = s2 + w * 1152;
    const int rrow = lane >> 2, cq = (lane & 3) * 16;
    #pragma unroll
    for (int i = 0; i < 4; ++i) {
        #pragma unroll
        for (int j = 0; j < 4; ++j)
            #pragma unroll
            for (int reg = 0; reg < 4; ++reg)
                wbuf[(fq * 4 + reg) * 72 + j * 16 + fm] = f2bf(acc[i][j][reg]);
        const int rl = wm * 64 + i * 16 + rrow;
        const int pr = s_pr[rl];
        if (pr >= 0) {
            unsigned short* dst = op + (size_t)pr * DIM + n0 + wn * 64 + cq;
            const short8 v0 = *(const short8*)&wbuf[rrow * 72 + cq];
            const short8 v1 = *(const short8*)&wbuf[rrow * 72 + cq + 8];
            *(short8*)dst = v0;
            *(short8*)(dst + 8) = v1;
        }
    }
}

// ---------------------------------------------------------------------------
// Combine: out[t] = w0*op[2t] + w1*op[2t+1]  (op bf16 -> out f32)
// ---------------------------------------------------------------------------
__global__ __launch_bounds__(256) void combine_kernel(
    const unsigned short* __restrict__ op, const float* __restrict__ pairw,
    float* __restrict__ out)
{
    const int f = blockIdx.x * 256 + threadIdx.x;   // over T*D/4
    const int t = f >> 8;
    const int c = f & 255;
    const float w0 = pairw[2 * t], w1 = pairw[2 * t + 1];
    const us4 a = ((const us4*)op)[(size_t)(2 * t) * (DIM / 4) + c];
    const us4 b = ((const us4*)op)[(size_t)(2 * t + 1) * (DIM / 4) + c];
    float4 r;
    r.x = w0 * __uint_as_float((unsigned)a.x << 16) + w1 * __uint_as_float((unsigned)b.x << 16);
    r.y = w0 * __uint_as_float((unsigned)a.y << 16) + w1 * __uint_as_float((unsigned)b.y << 16);
    r.z = w0 * __uint_as_float((unsigned)a.z << 16) + w1 * __uint_as_float((unsigned)b.z << 16);
    r.w = w0 * __uint_as_float((unsigned)a.w << 16) + w1 * __uint_as_float((unsigned)b.w << 16);
    ((float4*)out)[f] = r;
}

extern "C" void kernel_launch(void* const* d_in, const int* in_sizes, int n_in,
                              void* d_out, int out_size, void* d_ws, size_t ws_size,
                              hipStream_t stream)
{
    const float* x  = (const float*)d_in[0];
    const float* rw = (const float*)d_in[1];
    const float* wg = (const float*)d_in[2];
    const float* wu = (const float*)d_in[3];
    const float* wd = (const float*)d_in[4];
    float* out = (float*)d_out;
    char* ws = (char*)d_ws;

    int*   counts = (int*)(ws + OFF_CNT);
    float* usage  = (float*)(ws + OFF_USE);
    float* zacc   = (float*)(ws + OFF_Z);
    int*   offs   = (int*)(ws + OFF_OFFS);
    int*   lists  = (int*)(ws + OFF_LIST);
    float* pairw  = (float*)(ws + OFF_PAIRW);
    unsigned short* xb  = (unsigned short*)(ws + OFF_XB);
    unsigned short* hb  = (unsigned short*)(ws + OFF_H);
    unsigned short* B2  = (unsigned short*)(ws + OFF_B2);
    unsigned short* B1  = (unsigned short*)(ws + OFF_B1);
    unsigned short* op  = (unsigned short*)(ws + OFF_OP);

    hipMemsetAsync(ws, 0, 128, stream);

    router_kernel<<<T_TOK / 16, 256, 0, stream>>>(x, rw, counts, usage, zacc, lists, pairw, xb);

    conv_kernel<<<dim3(HP2 / 128, DIM / 128, 2 * NEXP), 256, 0, stream>>>(
        wg, wu, wd, B1, B2, counts, usage, zacc, offs, out);

    gemm1_kernel<<<dim3(HP2 / 128, T_TOK / 128, NEXP), 256, 0, stream>>>(xb, B1, counts, offs, lists, hb);
    gemm2_kernel<<<dim3(DIM / 128, T_TOK / 128, NEXP), 256, 0, stream>>>(hb, B2, counts, offs, lists, op);

    combine_kernel<<<(T_TOK * DIM / 4) / 256, 256, 0, stream>>>(op, pairw, out);
}